// Round 1
// baseline (2151.522 us; speedup 1.0000x reference)
//
#include <hip/hip_runtime.h>
#include <cstdint>
#include <cstddef>

#define BB 256
#define TT 4096
#define ID 63
#define HH 50
#define FCD 64

typedef float f32x2 __attribute__((ext_vector_type(2)));

__device__ __forceinline__ uint32_t rl_u32(float v, int lane) {
    return (uint32_t)__builtin_amdgcn_readlane(__float_as_int(v), lane);
}
__device__ __forceinline__ float rl_f(float v, int lane) {
    return __int_as_float(__builtin_amdgcn_readlane(__float_as_int(v), lane));
}
__device__ __forceinline__ uint64_t rlpair(float v, int kk) {
    uint32_t lo = rl_u32(v, 2 * kk);
    uint32_t hi = rl_u32(v, 2 * kk + 1);
    return (uint64_t)lo | ((uint64_t)hi << 32);
}

// D = S0 * S1 (packed fp32); hp is a 64-bit SGPR pair broadcast operand
__device__ __forceinline__ f32x2 pk_mul(uint64_t hp, f32x2 w) {
    f32x2 d;
    asm("v_pk_mul_f32 %0, %1, %2" : "=v"(d) : "s"(hp), "v"(w));
    return d;
}
// acc += hp * w (packed fp32, SGPR-pair broadcast operand)
__device__ __forceinline__ void pk_fma(f32x2& acc, uint64_t hp, f32x2 w) {
    asm("v_pk_fma_f32 %0, %1, %2, %0" : "+v"(acc) : "s"(hp), "v"(w));
}

__device__ __forceinline__ float fast_tanh(float x) {
    // tanh(x) = 1 - 2/(e^{2x}+1); exp2 overflow -> inf -> rcp -> 0 (correct +/-1 limits)
    float e = __builtin_amdgcn_exp2f(x * 2.88539008177792681472f); // 2*log2(e)
    return 1.0f - 2.0f * __builtin_amdgcn_rcpf(e + 1.0f);
}

// ---------------- Phase 1: z[b,t,j] = b_ih[j] + b_hh[j] + sum_i x[b,t,i]*W_ih[j,i]
// One wave per block, 64 rows per block. W rows via uniform (scalar) loads;
// two rows per iteration so row j+1's s_loads overlap row j's FMAs.
// Per-row summation order kept bit-identical to the verified baseline.
__global__ __launch_bounds__(64) void proj_kernel(
    const float* __restrict__ x, const float* __restrict__ W_ih,
    const float* __restrict__ b_ih, const float* __restrict__ b_hh,
    float* __restrict__ z)
{
    __shared__ float xs[64 * ID]; // 16128 B; reused as output staging (3200 floats)
    const int lane = threadIdx.x;
    const int64_t row0 = (int64_t)blockIdx.x * 64;

    // coalesced float4 stage of 64 rows (16128 B contiguous)
    const float4* __restrict__ xin4 = (const float4*)(x + row0 * ID);
    float4* xs4 = (float4*)xs;
    for (int i = lane; i < (64 * ID) / 4; i += 64) xs4[i] = xin4[i];
    __syncthreads();

    float xr[ID];
#pragma unroll
    for (int i = 0; i < ID; ++i) xr[i] = xs[lane * ID + i];
    __syncthreads(); // xs re-used as output staging below

    float* zs = xs;
#pragma unroll 1
    for (int j = 0; j < HH; j += 2) {
        const float* __restrict__ w0 = W_ih + j * ID;       // uniform -> s_load
        const float* __restrict__ w1 = w0 + ID;
        float a0 = b_ih[j] + b_hh[j],         a1 = 0.f, a2 = 0.f, a3 = 0.f;
        float c0 = b_ih[j + 1] + b_hh[j + 1], c1 = 0.f, c2 = 0.f, c3 = 0.f;
#pragma unroll
        for (int i = 0; i < 60; i += 4) {
            a0 = fmaf(xr[i + 0], w0[i + 0], a0);
            a1 = fmaf(xr[i + 1], w0[i + 1], a1);
            a2 = fmaf(xr[i + 2], w0[i + 2], a2);
            a3 = fmaf(xr[i + 3], w0[i + 3], a3);
            c0 = fmaf(xr[i + 0], w1[i + 0], c0);
            c1 = fmaf(xr[i + 1], w1[i + 1], c1);
            c2 = fmaf(xr[i + 2], w1[i + 2], c2);
            c3 = fmaf(xr[i + 3], w1[i + 3], c3);
        }
        a0 = fmaf(xr[60], w0[60], a0);
        a1 = fmaf(xr[61], w0[61], a1);
        a2 = fmaf(xr[62], w0[62], a2);
        c0 = fmaf(xr[60], w1[60], c0);
        c1 = fmaf(xr[61], w1[61], c1);
        c2 = fmaf(xr[62], w1[62], c2);
        zs[lane * HH + j]     = (a0 + a2) + (a1 + a3);
        zs[lane * HH + j + 1] = (c0 + c2) + (c1 + c3);
    }
    __syncthreads();

    // coalesced write-out: 64 rows x 50 floats = 12800 B contiguous
    const float2* zs2 = (const float2*)zs;
    float2* __restrict__ zo2 = (float2*)(z + row0 * HH);
#pragma unroll
    for (int i = lane; i < (64 * HH) / 2; i += 64) zo2[i] = zs2[i];
}

// ---------------- Phase 2: sequential recurrence, TWO batch elements per wave,
// software-pipelined in half-steps so each chain's dependency stalls are filled
// by the other chain's independent instructions.
//
// Phase (advance Y using broadcast hpY built last phase; rebuild hpX from vhX):
//   - 4 of Y's pk_fmas issue first (inputs ready) to cover vhX's tanh tail,
//   - then {readlane-pair(X), pk_fma(Y)} interleaved 1:1,
//   - tail readlanes fill Y's accumulator-drain + tanh latency.
// Per-step accumulation order identical to verified baseline (bitwise output).
__global__ __launch_bounds__(64) void rnn_kernel(
    const float* __restrict__ z, const float* __restrict__ W_hh,
    const float* __restrict__ W1, const float* __restrict__ b1,
    const float* __restrict__ W2, const float* __restrict__ b2,
    float* __restrict__ out)
{
    const int blk = blockIdx.x;               // 0..127
    const int bA = 2 * blk, bB = 2 * blk + 1;
    const int lane = threadIdx.x;
    const int j = (lane < HH) ? lane : (HH - 1);

    f32x2 wpk[25];
#pragma unroll
    for (int k = 0; k < 25; ++k) {
        wpk[k].x = W_hh[j * HH + 2 * k];
        wpk[k].y = W_hh[j * HH + 2 * k + 1];
    }

    const float* __restrict__ baseA = z + (int64_t)bA * TT * HH;
    const float* __restrict__ baseB = z + (int64_t)bB * TT * HH;
    const int col = j;

    float zpA[8], znA[8], zpB[8], znB[8];
#pragma unroll
    for (int u = 0; u < 8; ++u) {
        zpA[u] = baseA[u * HH + col];
        zpB[u] = baseB[u * HH + col];
    }
    const float* pA = baseA + 8 * HH;
    const float* pB = baseB + 8 * HH;

    float vhA = 0.f, vhB = 0.f;
    uint64_t hpA[25], hpB[25];
#pragma unroll
    for (int k = 0; k < 25; ++k) hpB[k] = 0;  // broadcast of vhB == 0

    for (int t0 = 0; t0 < TT; t0 += 8) {
        if (t0 + 8 < TT) { // uniform branch; last chunk has nothing to prefetch
#pragma unroll
            for (int u = 0; u < 8; ++u) {
                znA[u] = pA[u * HH + col];
                znB[u] = pB[u * HH + col];
            }
        }
        pA += 8 * HH;
        pB += 8 * HH;
#pragma unroll
        for (int u = 0; u < 8; ++u) {
            // ---- P1: advance B one step (consumes hpB); rebuild hpA from vhA
            {
                f32x2 a0 = pk_mul(hpB[0], wpk[0]);
                f32x2 a1 = pk_mul(hpB[1], wpk[1]);
                pk_fma(a0, hpB[2], wpk[2]);
                pk_fma(a1, hpB[3], wpk[3]);
#pragma unroll
                for (int kk = 0; kk < 21; ++kk) {
                    hpA[kk] = rlpair(vhA, kk);
                    const int m = kk + 4;
                    if (m & 1) pk_fma(a1, hpB[m], wpk[m]);
                    else       pk_fma(a0, hpB[m], wpk[m]);
                }
#pragma unroll
                for (int kk = 21; kk < 25; ++kk) hpA[kk] = rlpair(vhA, kk);
                f32x2 ab = a0 + a1;                          // v_pk_add_f32
                vhB = fast_tanh(zpB[u] + (ab.x + ab.y));
            }
            // ---- P2: advance A one step (consumes hpA); rebuild hpB from vhB
            {
                f32x2 a0 = pk_mul(hpA[0], wpk[0]);
                f32x2 a1 = pk_mul(hpA[1], wpk[1]);
                pk_fma(a0, hpA[2], wpk[2]);
                pk_fma(a1, hpA[3], wpk[3]);
#pragma unroll
                for (int kk = 0; kk < 21; ++kk) {
                    hpB[kk] = rlpair(vhB, kk);
                    const int m = kk + 4;
                    if (m & 1) pk_fma(a1, hpA[m], wpk[m]);
                    else       pk_fma(a0, hpA[m], wpk[m]);
                }
#pragma unroll
                for (int kk = 21; kk < 25; ++kk) hpB[kk] = rlpair(vhB, kk);
                f32x2 ab = a0 + a1;
                vhA = fast_tanh(zpA[u] + (ab.x + ab.y));
            }
        }
#pragma unroll
        for (int u = 0; u < 8; ++u) { zpA[u] = znA[u]; zpB[u] = znB[u]; }
    }

    // ---- MLP head + argmax for both chains (softmax monotone; tie -> 0, strict >)
    float fA = b1[lane];
    float fB = b1[lane];
#pragma unroll
    for (int k = 0; k < HH; ++k) {
        const float w1v = W1[lane * HH + k];
        fA = fmaf(rl_f(vhA, k), w1v, fA);
        fB = fmaf(rl_f(vhB, k), w1v, fB);
    }
    fA = fmaxf(fA, 0.f);
    fB = fmaxf(fB, 0.f);
    float p0A = fA * W2[lane], p1A = fA * W2[FCD + lane];
    float p0B = fB * W2[lane], p1B = fB * W2[FCD + lane];
#pragma unroll
    for (int off = 32; off > 0; off >>= 1) {
        p0A += __shfl_down(p0A, off, 64);
        p1A += __shfl_down(p1A, off, 64);
        p0B += __shfl_down(p0B, off, 64);
        p1B += __shfl_down(p1B, off, 64);
    }
    if (lane == 0) {
        out[bA] = ((p1A + b2[1]) > (p0A + b2[0])) ? 1.0f : 0.0f;
        out[bB] = ((p1B + b2[1]) > (p0B + b2[0])) ? 1.0f : 0.0f;
    }
}

// ---------------- Fallback: fully fused (used only if d_ws can't hold z)
__global__ __launch_bounds__(64) void rnn_fused_kernel(
    const float* __restrict__ x, const float* __restrict__ W_ih,
    const float* __restrict__ b_ih, const float* __restrict__ W_hh,
    const float* __restrict__ b_hh, const float* __restrict__ W1,
    const float* __restrict__ b1, const float* __restrict__ W2,
    const float* __restrict__ b2, float* __restrict__ out)
{
    const int b = blockIdx.x;
    const int lane = threadIdx.x;
    const int j = (lane < HH) ? lane : (HH - 1);

    float whh[HH];
#pragma unroll
    for (int k = 0; k < HH; ++k) whh[k] = W_hh[j * HH + k];
    float wih[ID];
#pragma unroll
    for (int i = 0; i < ID; ++i) wih[i] = W_ih[j * ID + i];
    const float bias = b_ih[j] + b_hh[j];

    const float* __restrict__ base = x + (int64_t)b * TT * ID;
    const int col = (lane < ID) ? lane : (ID - 1);

    float zp[8], zn[8];
#pragma unroll
    for (int u = 0; u < 8; ++u) zp[u] = base[u * ID + col];

    float vh = 0.f;
    for (int t0 = 0; t0 < TT; t0 += 8) {
        if (t0 + 8 < TT) {
#pragma unroll
            for (int u = 0; u < 8; ++u) zn[u] = base[(int64_t)(t0 + 8 + u) * ID + col];
        }
#pragma unroll
        for (int u = 0; u < 8; ++u) {
            float a0 = bias, a1 = 0.f, a2 = 0.f, a3 = 0.f;
#pragma unroll
            for (int i = 0; i < 60; i += 4) {
                a0 = fmaf(rl_f(zp[u], i + 0), wih[i + 0], a0);
                a1 = fmaf(rl_f(zp[u], i + 1), wih[i + 1], a1);
                a2 = fmaf(rl_f(zp[u], i + 2), wih[i + 2], a2);
                a3 = fmaf(rl_f(zp[u], i + 3), wih[i + 3], a3);
            }
            a0 = fmaf(rl_f(zp[u], 60), wih[60], a0);
            a1 = fmaf(rl_f(zp[u], 61), wih[61], a1);
            a2 = fmaf(rl_f(zp[u], 62), wih[62], a2);
#pragma unroll
            for (int k = 0; k < 48; k += 4) {
                a0 = fmaf(rl_f(vh, k + 0), whh[k + 0], a0);
                a1 = fmaf(rl_f(vh, k + 1), whh[k + 1], a1);
                a2 = fmaf(rl_f(vh, k + 2), whh[k + 2], a2);
                a3 = fmaf(rl_f(vh, k + 3), whh[k + 3], a3);
            }
            a0 = fmaf(rl_f(vh, 48), whh[48], a0);
            a1 = fmaf(rl_f(vh, 49), whh[49], a1);
            vh = fast_tanh((a0 + a2) + (a1 + a3));
        }
#pragma unroll
        for (int u = 0; u < 8; ++u) zp[u] = zn[u];
    }

    float f = b1[lane];
#pragma unroll
    for (int k = 0; k < HH; ++k) f = fmaf(rl_f(vh, k), W1[lane * HH + k], f);
    f = fmaxf(f, 0.f);
    float p0 = f * W2[lane];
    float p1 = f * W2[FCD + lane];
#pragma unroll
    for (int off = 32; off > 0; off >>= 1) {
        p0 += __shfl_down(p0, off, 64);
        p1 += __shfl_down(p1, off, 64);
    }
    if (lane == 0) out[b] = ((p1 + b2[1]) > (p0 + b2[0])) ? 1.0f : 0.0f;
}

extern "C" void kernel_launch(void* const* d_in, const int* in_sizes, int n_in,
                              void* d_out, int out_size, void* d_ws, size_t ws_size,
                              hipStream_t stream)
{
    const float* x    = (const float*)d_in[0];
    const float* W_ih = (const float*)d_in[1];
    const float* b_ih = (const float*)d_in[2];
    const float* W_hh = (const float*)d_in[3];
    const float* b_hh = (const float*)d_in[4];
    const float* W1   = (const float*)d_in[5];
    const float* b1   = (const float*)d_in[6];
    const float* W2   = (const float*)d_in[7];
    const float* b2   = (const float*)d_in[8];
    float* out = (float*)d_out;

    const size_t zbytes = (size_t)BB * TT * HH * sizeof(float);
    if (ws_size >= zbytes) {
        float* z = (float*)d_ws;
        proj_kernel<<<(BB * TT) / 64, 64, 0, stream>>>(x, W_ih, b_ih, b_hh, z);
        rnn_kernel<<<BB / 2, 64, 0, stream>>>(z, W_hh, W1, b1, W2, b2, out);
    } else {
        rnn_fused_kernel<<<BB, 64, 0, stream>>>(x, W_ih, b_ih, W_hh, b_hh,
                                                W1, b1, W2, b2, out);
    }
}

// Round 3
// 1457.130 us; speedup vs baseline: 1.4765x; 1.4765x over previous
//
#include <hip/hip_runtime.h>
#include <cstdint>
#include <cstddef>

#define BB 256
#define TT 4096
#define ID 63
#define HH 50
#define FCD 64

typedef float f32x2 __attribute__((ext_vector_type(2)));

__device__ __forceinline__ uint32_t rl_u32(float v, int lane) {
    return (uint32_t)__builtin_amdgcn_readlane(__float_as_int(v), lane);
}
__device__ __forceinline__ float rl_f(float v, int lane) {
    return __int_as_float(__builtin_amdgcn_readlane(__float_as_int(v), lane));
}

// D = S0 * S1 (packed fp32); hp is a 64-bit SGPR pair holding (h[2k], h[2k+1])
__device__ __forceinline__ f32x2 pk_mul(uint64_t hp, f32x2 w) {
    f32x2 d;
    asm("v_pk_mul_f32 %0, %1, %2" : "=v"(d) : "s"(hp), "v"(w));
    return d;
}
// acc += hp * w (packed fp32, SGPR-pair broadcast operand)
__device__ __forceinline__ void pk_fma(f32x2& acc, uint64_t hp, f32x2 w) {
    asm("v_pk_fma_f32 %0, %1, %2, %0" : "+v"(acc) : "s"(hp), "v"(w));
}
// acc += a * b (packed fp32, all-VGPR)
__device__ __forceinline__ void pk_fma_vv(f32x2& acc, f32x2 a, f32x2 b) {
    asm("v_pk_fma_f32 %0, %1, %2, %0" : "+v"(acc) : "v"(a), "v"(b));
}

__device__ __forceinline__ float fast_tanh(float x) {
    // tanh(x) = 1 - 2/(e^{2x}+1); exp2 overflow -> inf -> rcp -> 0 (correct +/-1 limits)
    float e = __builtin_amdgcn_exp2f(x * 2.88539008177792681472f); // 2*log2(e)
    return 1.0f - 2.0f * __builtin_amdgcn_rcpf(e + 1.0f);
}

// ---------------- Phase 1: z[b,t,j] = b_ih[j] + b_hh[j] + sum_i x[b,t,i]*W_ih[j,i]
// One wave per block, 64 rows per block. v2: W_ih staged once per block into LDS
// (rows padded to 64 floats, bias in pad slot 63); j-loop reads W via broadcast
// ds_read_b128 (pipelines with FMAs, no per-row s_load stall); x pairs in VGPRs
// feed all-VGPR v_pk_fma_f32 (halves FMA issue count).
__global__ __launch_bounds__(64) void proj_kernel(
    const float* __restrict__ x, const float* __restrict__ W_ih,
    const float* __restrict__ b_ih, const float* __restrict__ b_hh,
    float* __restrict__ z)
{
    __shared__ __align__(16) float xs[64 * ID];   // 16128 B; x stage, reused as z staging
    __shared__ __align__(16) float ws[HH * 64];   // 12800 B; W rows padded, col 63 = bias
    const int lane = threadIdx.x;
    const int64_t row0 = (int64_t)blockIdx.x * 64;

    // coalesced float4 stage of 64 rows of x (16128 B contiguous)
    const float4* __restrict__ xin4 = (const float4*)(x + row0 * ID);
    float4* xs4 = (float4*)xs;
#pragma unroll
    for (int i = lane; i < (64 * ID) / 4; i += 64) xs4[i] = xin4[i];

    // stage W (coalesced 252B rows; L2-hot after first blocks) + bias in pad slot
    if (lane < ID) {
#pragma unroll 2
        for (int r = 0; r < HH; ++r) ws[r * 64 + lane] = W_ih[r * ID + lane];
    }
    if (lane < HH) ws[lane * 64 + ID] = b_ih[lane] + b_hh[lane];
    __syncthreads();

    // per-lane x row -> register pairs
    f32x2 xp[31];
    float x62;
#pragma unroll
    for (int p = 0; p < 31; ++p) {
        xp[p].x = xs[lane * ID + 2 * p];
        xp[p].y = xs[lane * ID + 2 * p + 1];
    }
    x62 = xs[lane * ID + 62];
    __syncthreads(); // xs re-used as z staging below

    float* zs = xs;
#pragma unroll 2
    for (int j = 0; j < HH; ++j) {
        const float4* __restrict__ w4 = (const float4*)(ws + j * 64); // broadcast reads
        f32x2 c0 = {0.f, 0.f}, c1 = {0.f, 0.f};
#pragma unroll
        for (int m = 0; m < 15; ++m) {
            float4 q = w4[m];
            f32x2 wlo; wlo.x = q.x; wlo.y = q.y;
            f32x2 whi; whi.x = q.z; whi.y = q.w;
            pk_fma_vv(c0, xp[2 * m + 0], wlo);
            pk_fma_vv(c1, xp[2 * m + 1], whi);
        }
        float4 qt = w4[15]; // w60, w61, w62, bias
        f32x2 wlo; wlo.x = qt.x; wlo.y = qt.y;
        pk_fma_vv(c0, xp[30], wlo);
        float s = (c0.x + c1.x) + (c0.y + c1.y) + fmaf(x62, qt.z, qt.w);
        zs[lane * HH + j] = s;
    }
    __syncthreads();

    // coalesced write-out: 64 rows x 50 floats = 12800 B contiguous
    const float2* zs2 = (const float2*)zs;
    float2* __restrict__ zo2 = (float2*)(z + row0 * HH);
#pragma unroll
    for (int i = lane; i < (64 * HH) / 2; i += 64) zo2[i] = zs2[i];
}

// ---------------- Phase 2: sequential recurrence, one wave per batch element.
// Packed-fp32 matvec: 25 v_pk_fma_f32 with SGPR-pair broadcast of (h[2k],h[2k+1]).
// (Verified 837us single-chain version; dual-chain pipelining measured
// issue-bound-neutral and regressed wall time.)
__global__ __launch_bounds__(64) void rnn_kernel(
    const float* __restrict__ z, const float* __restrict__ W_hh,
    const float* __restrict__ W1, const float* __restrict__ b1,
    const float* __restrict__ W2, const float* __restrict__ b2,
    float* __restrict__ out)
{
    const int b = blockIdx.x;
    const int lane = threadIdx.x;
    const int j = (lane < HH) ? lane : (HH - 1);

    f32x2 wpk[25];
#pragma unroll
    for (int k = 0; k < 25; ++k) {
        wpk[k].x = W_hh[j * HH + 2 * k];
        wpk[k].y = W_hh[j * HH + 2 * k + 1];
    }

    const float* __restrict__ base = z + (int64_t)b * TT * HH;
    const int col = j;

    float zp[8], zn[8];
#pragma unroll
    for (int u = 0; u < 8; ++u) zp[u] = base[u * HH + col];
    const float* p = base + 8 * HH;

    float vh = 0.f;
    for (int t0 = 0; t0 < TT; t0 += 8) {
        if (t0 + 8 < TT) { // uniform branch; last chunk has nothing to prefetch
#pragma unroll
            for (int u = 0; u < 8; ++u) zn[u] = p[u * HH + col];
        }
        p += 8 * HH;
#pragma unroll
        for (int u = 0; u < 8; ++u) {
            uint64_t hp[25];
#pragma unroll
            for (int k = 0; k < 25; ++k) {
                uint32_t lo = rl_u32(vh, 2 * k);
                uint32_t hi = rl_u32(vh, 2 * k + 1);
                hp[k] = (uint64_t)lo | ((uint64_t)hi << 32);
            }
            f32x2 accA = pk_mul(hp[0], wpk[0]);
            f32x2 accB = pk_mul(hp[1], wpk[1]);
#pragma unroll
            for (int k = 2; k < 25; k += 2) pk_fma(accA, hp[k], wpk[k]);
#pragma unroll
            for (int k = 3; k < 25; k += 2) pk_fma(accB, hp[k], wpk[k]);
            f32x2 ab = accA + accB;                 // v_pk_add_f32
            float s = zp[u] + (ab.x + ab.y);
            vh = fast_tanh(s);
        }
#pragma unroll
        for (int u = 0; u < 8; ++u) zp[u] = zn[u];
    }

    // ---- MLP head + argmax (softmax monotone; np.argmax tie -> 0, so strict >)
    float f = b1[lane];
#pragma unroll
    for (int k = 0; k < HH; ++k) f = fmaf(rl_f(vh, k), W1[lane * HH + k], f);
    f = fmaxf(f, 0.f);
    float p0 = f * W2[lane];
    float p1 = f * W2[FCD + lane];
#pragma unroll
    for (int off = 32; off > 0; off >>= 1) {
        p0 += __shfl_down(p0, off, 64);
        p1 += __shfl_down(p1, off, 64);
    }
    if (lane == 0) out[b] = ((p1 + b2[1]) > (p0 + b2[0])) ? 1.0f : 0.0f;
}

// ---------------- Fallback: fully fused (used only if d_ws can't hold z)
__global__ __launch_bounds__(64) void rnn_fused_kernel(
    const float* __restrict__ x, const float* __restrict__ W_ih,
    const float* __restrict__ b_ih, const float* __restrict__ W_hh,
    const float* __restrict__ b_hh, const float* __restrict__ W1,
    const float* __restrict__ b1, const float* __restrict__ W2,
    const float* __restrict__ b2, float* __restrict__ out)
{
    const int b = blockIdx.x;
    const int lane = threadIdx.x;
    const int j = (lane < HH) ? lane : (HH - 1);

    float whh[HH];
#pragma unroll
    for (int k = 0; k < HH; ++k) whh[k] = W_hh[j * HH + k];
    float wih[ID];
#pragma unroll
    for (int i = 0; i < ID; ++i) wih[i] = W_ih[j * ID + i];
    const float bias = b_ih[j] + b_hh[j];

    const float* __restrict__ base = x + (int64_t)b * TT * ID;
    const int col = (lane < ID) ? lane : (ID - 1);

    float zp[8], zn[8];
#pragma unroll
    for (int u = 0; u < 8; ++u) zp[u] = base[u * ID + col];

    float vh = 0.f;
    for (int t0 = 0; t0 < TT; t0 += 8) {
        if (t0 + 8 < TT) {
#pragma unroll
            for (int u = 0; u < 8; ++u) zn[u] = base[(int64_t)(t0 + 8 + u) * ID + col];
        }
#pragma unroll
        for (int u = 0; u < 8; ++u) {
            float a0 = bias, a1 = 0.f, a2 = 0.f, a3 = 0.f;
#pragma unroll
            for (int i = 0; i < 60; i += 4) {
                a0 = fmaf(rl_f(zp[u], i + 0), wih[i + 0], a0);
                a1 = fmaf(rl_f(zp[u], i + 1), wih[i + 1], a1);
                a2 = fmaf(rl_f(zp[u], i + 2), wih[i + 2], a2);
                a3 = fmaf(rl_f(zp[u], i + 3), wih[i + 3], a3);
            }
            a0 = fmaf(rl_f(zp[u], 60), wih[60], a0);
            a1 = fmaf(rl_f(zp[u], 61), wih[61], a1);
            a2 = fmaf(rl_f(zp[u], 62), wih[62], a2);
#pragma unroll
            for (int k = 0; k < 48; k += 4) {
                a0 = fmaf(rl_f(vh, k + 0), whh[k + 0], a0);
                a1 = fmaf(rl_f(vh, k + 1), whh[k + 1], a1);
                a2 = fmaf(rl_f(vh, k + 2), whh[k + 2], a2);
                a3 = fmaf(rl_f(vh, k + 3), whh[k + 3], a3);
            }
            a0 = fmaf(rl_f(vh, 48), whh[48], a0);
            a1 = fmaf(rl_f(vh, 49), whh[49], a1);
            vh = fast_tanh((a0 + a2) + (a1 + a3));
        }
#pragma unroll
        for (int u = 0; u < 8; ++u) zp[u] = zn[u];
    }

    float f = b1[lane];
#pragma unroll
    for (int k = 0; k < HH; ++k) f = fmaf(rl_f(vh, k), W1[lane * HH + k], f);
    f = fmaxf(f, 0.f);
    float p0 = f * W2[lane];
    float p1 = f * W2[FCD + lane];
#pragma unroll
    for (int off = 32; off > 0; off >>= 1) {
        p0 += __shfl_down(p0, off, 64);
        p1 += __shfl_down(p1, off, 64);
    }
    if (lane == 0) out[b] = ((p1 + b2[1]) > (p0 + b2[0])) ? 1.0f : 0.0f;
}

extern "C" void kernel_launch(void* const* d_in, const int* in_sizes, int n_in,
                              void* d_out, int out_size, void* d_ws, size_t ws_size,
                              hipStream_t stream)
{
    const float* x    = (const float*)d_in[0];
    const float* W_ih = (const float*)d_in[1];
    const float* b_ih = (const float*)d_in[2];
    const float* W_hh = (const float*)d_in[3];
    const float* b_hh = (const float*)d_in[4];
    const float* W1   = (const float*)d_in[5];
    const float* b1   = (const float*)d_in[6];
    const float* W2   = (const float*)d_in[7];
    const float* b2   = (const float*)d_in[8];
    float* out = (float*)d_out;

    const size_t zbytes = (size_t)BB * TT * HH * sizeof(float);
    if (ws_size >= zbytes) {
        float* z = (float*)d_ws;
        proj_kernel<<<(BB * TT) / 64, 64, 0, stream>>>(x, W_ih, b_ih, b_hh, z);
        rnn_kernel<<<BB, 64, 0, stream>>>(z, W_hh, W1, b1, W2, b2, out);
    } else {
        rnn_fused_kernel<<<BB, 64, 0, stream>>>(x, W_ih, b_ih, W_hh, b_hh,
                                                W1, b1, W2, b2, out);
    }
}